// Round 5
// baseline (63.792 us; speedup 1.0000x reference)
//
#include <hip/hip_runtime.h>
#include <hip/hip_bf16.h>

typedef __attribute__((ext_vector_type(8))) short bf16x8;
typedef __attribute__((ext_vector_type(4))) float f32x4;

#define D 1024
#define NROWS 4096          // B
#define SCALE_U 14.426950408889634f   // (1/T) * log2(e)
#define LN2 0.69314718055994530942f
#define NCC 32              // column chunks — one 128-col block each
#define BM 128              // block tile rows/cols
#define BK 64               // K slab

// ---------------- workspace layout ----------------
// zn      : 8192*1024 bf16 (z1 rows pre-scaled by SCALE_U)   @ 0         (16 MiB)
// pmax    : 4096*32 f32                                      @ 16777216  (512 KiB)
// psum    : 4096*32 f32                                      @ 17301504  (512 KiB)
// diag    : 4096 f32                                         @ 17825792  (16 KiB)
// contrib : 4096 f32                                         @ 17842176  (16 KiB)

__device__ __forceinline__ unsigned short f2bf(float x) {
    __hip_bfloat16 h = __float2bfloat16(x);
    return *reinterpret_cast<unsigned short*>(&h);
}
__device__ __forceinline__ void gload16(const unsigned short* g, unsigned short* l) {
    __builtin_amdgcn_global_load_lds((const __attribute__((address_space(1))) void*)g,
                                     (__attribute__((address_space(3))) void*)l, 16, 0, 0);
}

// ---------- 1. row normalize + bf16 cast (z1 scaled by SCALE_U) ----------
__global__ __launch_bounds__(256) void nrm_kernel(const float* __restrict__ feat,
                                                  unsigned short* __restrict__ zn) {
    const int row = blockIdx.x;           // 0..8191
    const int tid = threadIdx.x;          // 256, 4 floats each
    const float4 v = reinterpret_cast<const float4*>(feat + (size_t)row * D)[tid];
    float ss = v.x * v.x + v.y * v.y + v.z * v.z + v.w * v.w;
#pragma unroll
    for (int off = 32; off > 0; off >>= 1) ss += __shfl_down(ss, off);
    __shared__ float red[4];
    const int lane = tid & 63, wid = tid >> 6;
    if (lane == 0) red[wid] = ss;
    __syncthreads();
    const float tot = red[0] + red[1] + red[2] + red[3];
    const float nrm = fmaxf(sqrtf(tot), 1e-8f);
    const float sc = ((row < NROWS) ? SCALE_U : 1.0f) / nrm;
    ushort4 o;
    o.x = f2bf(v.x * sc);
    o.y = f2bf(v.y * sc);
    o.z = f2bf(v.z * sc);
    o.w = f2bf(v.w * sc);
    reinterpret_cast<ushort4*>(zn + (size_t)row * D)[tid] = o;
}

// ---------- 2. Gram (u = logits*log2e) + fused LSE partials ----------
// R2-proven structure: 128x128 tile, 256 threads = 4 waves (2x2), wave tile 64x64,
// global_load_lds width=16 staging (linear LDS dest, pre-swizzled global source,
// swizzled ds_read — both-sides rule), 4 blocks/CU for wave-level overlap.
// Added: XCD-aware 16x8-region block swizzle (bijective, 1024%8==0) for L2
// locality; diagonal u_ii extraction on the 32 rt==cc blocks.
__global__ __launch_bounds__(256, 4) void gram_lse_kernel(const unsigned short* __restrict__ zn,
                                                          float* __restrict__ pmax,
                                                          float* __restrict__ psum,
                                                          float* __restrict__ diag) {
    __shared__ __align__(16) unsigned short As[BM * BK];
    __shared__ __align__(16) unsigned short Bs[BM * BK];
    __shared__ float mbuf[BM][2];
    __shared__ float sbuf[BM][2];

    // XCD-aware swizzle: XCD x covers a 16-rowtile x 8-coltile region (6 MB panels)
    const int bid = blockIdx.x;            // 0..1023
    const int xcd = bid & 7, t = bid >> 3; // t: 0..127 within XCD
    const int rt = (xcd >> 2) * 16 + (t >> 3);   // 0..31
    const int cc = (xcd & 3) * 8 + (t & 7);      // 0..31

    const int tid = threadIdx.x;
    const int lane = tid & 63;
    const int wid  = tid >> 6;        // 0..3
    const int wm = wid >> 1, wn = wid & 1;
    const int l15 = lane & 15, g = lane >> 4;

    const unsigned short* z1 = zn;
    const unsigned short* z2 = zn + (size_t)NROWS * D;

    // staging lane constants: 8 lanes per row (8 x 16B = 128B row), source chunk
    // pre-swizzled so LDS[row][j] = global[row][j ^ (row&7)]
    const int lrow8  = lane >> 3;     // 0..7 (also row&7 since r0 is mult of 8)
    const int cs     = (lane & 7) ^ lrow8;
    const int colbase = cc * BM;

    f32x4 acc[4][4];
#pragma unroll
    for (int i = 0; i < 4; i++)
#pragma unroll
        for (int j = 0; j < 4; j++) acc[i][j] = (f32x4){0.f, 0.f, 0.f, 0.f};

    for (int kb = 0; kb < D / BK; ++kb) {
        __syncthreads();   // previous-iter readers done before overwrite
#pragma unroll
        for (int it = 0; it < 4; ++it) {
            const int r0 = (wid * 4 + it) * 8;              // wave-uniform row base
            gload16(z1 + (size_t)(rt * BM + r0 + lrow8) * D + kb * BK + cs * 8,
                    &As[r0 * BK]);
            gload16(z2 + (size_t)(colbase + r0 + lrow8) * D + kb * BK + cs * 8,
                    &Bs[r0 * BK]);
        }
        __syncthreads();   // vmcnt(0) drain: LDS tiles ready
#pragma unroll
        for (int kk = 0; kk < 2; ++kk) {
            bf16x8 a[4], b[4];
#pragma unroll
            for (int fr = 0; fr < 4; ++fr) {
                const int row = wm * 64 + fr * 16 + l15;
                const int pc = (kk * 4 + g) ^ (row & 7);
                a[fr] = *reinterpret_cast<const bf16x8*>(&As[row * BK + pc * 8]);
            }
#pragma unroll
            for (int fn = 0; fn < 4; ++fn) {
                const int row = wn * 64 + fn * 16 + l15;
                const int pc = (kk * 4 + g) ^ (row & 7);
                b[fn] = *reinterpret_cast<const bf16x8*>(&Bs[row * BK + pc * 8]);
            }
#pragma unroll
            for (int fr = 0; fr < 4; ++fr)
#pragma unroll
                for (int fn = 0; fn < 4; ++fn)
                    acc[fr][fn] = __builtin_amdgcn_mfma_f32_16x16x32_bf16(a[fr], b[fn], acc[fr][fn], 0, 0, 0);
        }
    }

    // ---- diagonal extraction (u_ii) on the 32 rt==cc blocks ----
    if (rt == cc) {
#pragma unroll
        for (int fr = 0; fr < 4; ++fr)
#pragma unroll
            for (int fn = 0; fn < 4; ++fn)
#pragma unroll
                for (int r = 0; r < 4; ++r) {
                    const int rl = wm * 64 + fr * 16 + g * 4 + r;
                    const int cl = wn * 64 + fn * 16 + l15;
                    if (rl == cl) diag[rt * BM + rl] = acc[fr][fn][r];
                }
    }

    // per-row tile max/sum (values already in exp2 domain), butterfly across the
    // 16 lanes of each group (cols), then across wn via LDS
#pragma unroll
    for (int fr = 0; fr < 4; ++fr) {
#pragma unroll
        for (int r = 0; r < 4; ++r) {
            const float v0 = acc[fr][0][r], v1 = acc[fr][1][r];
            const float v2 = acc[fr][2][r], v3 = acc[fr][3][r];
            float m = fmaxf(fmaxf(v0, v1), fmaxf(v2, v3));
            float s = exp2f(v0 - m) + exp2f(v1 - m) + exp2f(v2 - m) + exp2f(v3 - m);
#pragma unroll
            for (int off = 1; off < 16; off <<= 1) {
                const float om = __shfl_xor(m, off);
                const float os = __shfl_xor(s, off);
                const float nm = fmaxf(m, om);
                s = s * exp2f(m - nm) + os * exp2f(om - nm);
                m = nm;
            }
            if (l15 == 0) {
                const int rloc = wm * 64 + fr * 16 + g * 4 + r;
                mbuf[rloc][wn] = m;
                sbuf[rloc][wn] = s;
            }
        }
    }
    __syncthreads();
    if (tid < BM) {
        const float m0 = mbuf[tid][0], m1 = mbuf[tid][1];
        const float s0 = sbuf[tid][0], s1 = sbuf[tid][1];
        const float nm = fmaxf(m0, m1);
        const float s = s0 * exp2f(m0 - nm) + s1 * exp2f(m1 - nm);
        const int grow = rt * BM + tid;
        pmax[grow * NCC + cc] = nm;
        psum[grow * NCC + cc] = s;
    }
}

// ---------- 3. per-row partial combine (diag precomputed in gram) ----------
__global__ __launch_bounds__(256) void rowfinal_kernel(const float* __restrict__ pmax,
                                                       const float* __restrict__ psum,
                                                       const float* __restrict__ diag,
                                                       float* __restrict__ contrib) {
    const int i = blockIdx.x * 256 + threadIdx.x;   // row 0..4095
    float4 pm[8], ps[8];
#pragma unroll
    for (int q = 0; q < 8; ++q) {
        pm[q] = reinterpret_cast<const float4*>(pmax + (size_t)i * NCC)[q];
        ps[q] = reinterpret_cast<const float4*>(psum + (size_t)i * NCC)[q];
    }
    float m = -INFINITY;
#pragma unroll
    for (int q = 0; q < 8; ++q)
        m = fmaxf(m, fmaxf(fmaxf(pm[q].x, pm[q].y), fmaxf(pm[q].z, pm[q].w)));
    float s = 0.f;
#pragma unroll
    for (int q = 0; q < 8; ++q) {
        s += ps[q].x * exp2f(pm[q].x - m);
        s += ps[q].y * exp2f(pm[q].y - m);
        s += ps[q].z * exp2f(pm[q].z - m);
        s += ps[q].w * exp2f(pm[q].w - m);
    }
    contrib[i] = m + log2f(s) - diag[i];   // exp2-domain LSE minus u_ii
}

// ---------- 4. deterministic final reduce ----------
__global__ __launch_bounds__(256) void final_kernel(const float* __restrict__ contrib,
                                                    float* __restrict__ out) {
    const int tid = threadIdx.x;
    float s = 0.f;
    for (int j = tid; j < NROWS; j += 256) s += contrib[j];
#pragma unroll
    for (int off = 32; off > 0; off >>= 1) s += __shfl_down(s, off);
    __shared__ float red[4];
    const int lane = tid & 63, wid = tid >> 6;
    if (lane == 0) red[wid] = s;
    __syncthreads();
    if (tid == 0) out[0] = (red[0] + red[1] + red[2] + red[3]) * (LN2 / (float)NROWS);
}

extern "C" void kernel_launch(void* const* d_in, const int* in_sizes, int n_in,
                              void* d_out, int out_size, void* d_ws, size_t ws_size,
                              hipStream_t stream) {
    const float* feat = (const float*)d_in[0];
    unsigned short* zn = (unsigned short*)d_ws;
    float* pmax    = (float*)((char*)d_ws + 16777216);
    float* psum    = (float*)((char*)d_ws + 17301504);
    float* diag    = (float*)((char*)d_ws + 17825792);
    float* contrib = (float*)((char*)d_ws + 17842176);
    float* out = (float*)d_out;

    nrm_kernel<<<8192, 256, 0, stream>>>(feat, zn);
    gram_lse_kernel<<<1024, 256, 0, stream>>>(zn, pmax, psum, diag);
    rowfinal_kernel<<<16, 256, 0, stream>>>(pmax, psum, diag, contrib);
    final_kernel<<<1, 256, 0, stream>>>(contrib, out);
}